// Round 12
// baseline (492.627 us; speedup 1.0000x reference)
//
#include <hip/hip_runtime.h>
#include <hip/hip_bf16.h>
#include <hip/hip_cooperative_groups.h>
namespace cg = cooperative_groups;

// ---- problem constants ----
constexpr int NN = 16000, NE = 48000, NF = 32000;
constexpr int ND = 64, NB = 32, NG = 32;
constexpr int HIDN = 256, NCLS = 10;
constexpr int GRID = 768, BLK = 256, GTH = GRID * BLK;  // 196608 threads
constexpr int CHB = 24;                    // ecc blocks per graph (768/32)
constexpr int CAPE = 4096, CAPF = 4096;    // bucket capacity (mean 1500/1000, +60 sigma)
constexpr float KLOG = 144.26950408889634f;     // 100*log2(e)
constexpr float DLT  = 9.307710457348151f;      // (2/31)*KLOG
constexpr float INV_DLT = 0.10743849569269015f;
constexpr int HBINS = 35;                  // 32 real + 3 pad (max write jlo+3 <= 34)

// ---- ws word layout (~4.9 MB of the 268 MB ws) ----
constexpr int NH_OFF   = 0;                        // [NN*ND] f32 node heights
constexpr int ECCF_OFF = NH_OFF + NN * ND;         // [65536] f32 ecc (+64 cursors after)
constexpr int CUR_OFF  = ECCF_OFF + NG * NB * ND;  // [64] u32 append cursors
constexpr int NOFS_OFF = CUR_OFF + 64;             // [36] i32 node boundaries
constexpr int PE_OFF   = NOFS_OFF + 36;            // u16[NG*CAPE]
constexpr int PF_OFF   = PE_OFF + NG * CAPE / 2;   // u16[NG*CAPF]
constexpr int HB_OFF   = PF_OFF + NG * CAPF / 2;   // [NG*HIDN] f32 hidden acts

__device__ __forceinline__ int clamp_node(int n) {
    return ((unsigned)n < (unsigned)NN) ? n : 0;
}
template<bool BF> __device__ __forceinline__ float ldf(const void* p, int i) {
    return BF ? __bfloat162float(((const __hip_bfloat16*)p)[i]) : ((const float*)p)[i];
}
template<bool I64> __device__ __forceinline__ int ldi(const int* p, int i) {
    return I64 ? p[2 * i] : p[i];
}
__device__ __forceinline__ bool detect_bf(const void* xp) {
    const unsigned* xw = (const unsigned*)xp;
    unsigned w = xw[threadIdx.x & 63];
    return __ballot(((w >> 23) & 0xFFu) >= 200u) != 0ull;
}
__device__ __forceinline__ bool detect_i64(const int* eip) {
    const unsigned* eiw = (const unsigned*)eip;
    unsigned o = eiw[2 * (threadIdx.x & 63) + 1];
    return __ballot(o != 0u) == 0ull;
}

// 4-tap delta-histogram sigmoid: 3 exact rcp taps + saturation step.
// T=14: bins before window have sigma<=6.1e-5 (snapped 0), after window
// sigma>=1-6.5e-5 (snapped 1). Lane d owns column d of its wave's copy: plain RMW.
__device__ __forceinline__ void accum_hist(float h, float s, float* hb) {
    const float KDEC = __builtin_amdgcn_exp2f(-DLT);
    float hkL = fmaf(h, KLOG, KLOG);              // t_j = hkL - j*DLT
    float fl = floorf((hkL - 14.0f) * INV_DLT);
    int jlo = (int)fl + 1;                        // first j with t_j < 14
    if (jlo >= 32) return;                        // everything ~0
    float t0 = fmaf(-(fl + 1.0f), DLT, hkL);      // t at jlo, in [4.69, 14)
    float e = __builtin_amdgcn_exp2f(t0);
    float prev = 0.0f;
#pragma unroll
    for (int m = 0; m < 3; m++) {
        float sig = __builtin_amdgcn_rcpf(1.0f + e);
        int idx = max(jlo + m, 0);
        hb[idx * 64] += s * (sig - prev);
        prev = sig; e *= KDEC;
    }
    int idx3 = max(jlo + 3, 0);
    hb[idx3 * 64] += s * (1.0f - prev);
}

template<bool BF, bool I64>
__device__ __forceinline__ void all_body(const int* ei, const int* fc, const int* batch,
                                         const void* x, const void* nw, const void* v,
                                         const void* ew, const void* fw,
                                         const void* W1, const void* b1,
                                         const void* W2, const void* b2,
                                         float* wsf, void* outv,
                                         float* scr, unsigned* cnt, unsigned* base,
                                         cg::grid_group& grid) {
    int t = threadIdx.x;
    int b = blockIdx.x;
    int gid = b * BLK + t;
    unsigned* wsu = (unsigned*)wsf;
    int* wsi = (int*)wsf;
    float* nh   = wsf + NH_OFF;
    float* eccf = wsf + ECCF_OFF;
    unsigned* cur = wsu + CUR_OFF;
    int* nofs = wsi + NOFS_OFF;
    unsigned short* pe = (unsigned short*)(wsi + PE_OFF);
    unsigned short* pf = (unsigned short*)(wsi + PF_OFF);
    float* hbuf = wsf + HB_OFF;

    // ---- P0: zero eccf+cursors, node heights, node boundaries ----
    for (int idx = gid; idx < NG * NB * ND + 64; idx += GTH) eccf[idx] = 0.0f;
    for (int idx = gid; idx < NN * ND; idx += GTH) {
        int n = idx >> 6, d = idx & 63;
        nh[idx] = fmaf(ldf<BF>(x, n*3+2), ldf<BF>(v, 2*ND+d),
                  fmaf(ldf<BF>(x, n*3+1), ldf<BF>(v, ND+d),
                       ldf<BF>(x, n*3+0) * ldf<BF>(v, d))) * ldf<BF>(nw, n);
    }
    if (gid < NN) {
        int gn = ldi<I64>(batch, gid) & (NG - 1);
        int gp = (gid > 0) ? (ldi<I64>(batch, gid - 1) & (NG - 1)) : -1;
        for (int gg = gp + 1; gg <= gn; gg++) nofs[gg] = gid;
        if (gid == NN - 1)
            for (int gg = gn + 1; gg <= NG; gg++) nofs[gg] = NN;
    }
    grid.sync();

    // ---- P1: append-scatter edges/faces into fixed-capacity buckets ----
    if (b < (NE + NF + BLK - 1) / BLK) {
        if (t < 64) cnt[t] = 0;
        __syncthreads();
        int bin = 0; unsigned rank = 0; bool act = false;
        if (gid < NE + NF) {
            if (gid < NE) bin = ldi<I64>(batch, clamp_node(ldi<I64>(ei, gid))) & 31;
            else bin = 32 + (ldi<I64>(batch, clamp_node(ldi<I64>(fc, gid - NE))) & 31);
            act = true;
            rank = atomicAdd(&cnt[bin], 1u);
        }
        __syncthreads();
        if (t < 64) base[t] = cnt[t] ? atomicAdd(&cur[t], cnt[t]) : 0u;
        __syncthreads();
        if (act) {
            int off = (int)(base[bin] + rank);
            if (bin < 32) { if (off < CAPE) pe[bin * CAPE + off] = (unsigned short)gid; }
            else { if (off < CAPF) pf[(bin - 32) * CAPF + off] = (unsigned short)(gid - NE); }
        }
    }
    grid.sync();

    // ---- P2: ecc via wave-private LDS delta-histograms ----
    {
        float* hist = scr;                        // 4*HBINS*64
        int d = t & 63;
        int w = __builtin_amdgcn_readfirstlane(t) >> 6;
        int g = b / CHB, cb = b % CHB;
        int sid = cb * 4 + w;
        const int S = CHB * 4;                    // 96 streams per graph
        for (int j = t; j < 4 * HBINS * 64; j += BLK) hist[j] = 0.0f;
        __syncthreads();
        float* hb = hist + w * (HBINS * 64) + d;

        int ns = nofs[g], nend = nofs[g + 1];
        for (int i = ns + sid; i < nend; i += S)
            accum_hist(nh[i * ND + d], 1.0f, hb);

        int ecnt = min((int)cur[g], CAPE);
        for (int i = sid; i < ecnt; i += S) {
            int e = pe[g * CAPE + i];
            int a = clamp_node(ldi<I64>(ei, e)), bb = clamp_node(ldi<I64>(ei, NE + e));
            accum_hist(fmaxf(nh[a*ND+d], nh[bb*ND+d]) * ldf<BF>(ew, e), -1.0f, hb);
        }
        int fcnt = min((int)cur[32 + g], CAPF);
        for (int i = sid; i < fcnt; i += S) {
            int f = pf[g * CAPF + i];
            int a = clamp_node(ldi<I64>(fc, f)), bb = clamp_node(ldi<I64>(fc, NF + f));
            int cc = clamp_node(ldi<I64>(fc, 2*NF + f));
            accum_hist(fmaxf(fmaxf(nh[a*ND+d], nh[bb*ND+d]), nh[cc*ND+d]) * ldf<BF>(fw, f),
                       1.0f, hb);
        }
        __syncthreads();
        for (int o = t; o < HBINS * 64; o += BLK)
            hist[o] += hist[HBINS*64 + o] + hist[2*HBINS*64 + o] + hist[3*HBINS*64 + o];
        __syncthreads();
        if (t < 64) {
            float run = 0.0f;
            float* eb = eccf + g * (NB * ND) + t;
            for (int j = 0; j < 32; j++) {
                run += hist[j * 64 + t];
                atomicAdd(eb + j * 64, run);
            }
        }
    }
    grid.sync();

    // ---- P3: MLP layer 1 + flat-output flush (blocks 0..255) ----
    if (b < NG * 8) {
        float* red = scr;                         // 256*33
        float* pr  = scr + 256 * 33;              // 256
        int g = b >> 3, hc = b & 7;

        const float4* fp = (const float4*)(eccf + g * (NB * ND) + t * 8);
        float4 fa = fp[0], fb = fp[1];
        float fl[8] = {fa.x, fa.y, fa.z, fa.w, fb.x, fb.y, fb.z, fb.w};

        if (hc == 0) {
            int ob = NG * NCLS + g * (NB * ND) + t * 8;
            if (BF) {
#pragma unroll
                for (int j = 0; j < 8; j++)
                    ((__hip_bfloat16*)outv)[ob + j] = __float2bfloat16(fl[j]);
            } else {
                ((float4*)((float*)outv + ob))[0] = fa;
                ((float4*)((float*)outv + ob))[1] = fb;
            }
        }

        float acc[32];
#pragma unroll
        for (int r = 0; r < 32; r++) acc[r] = 0.0f;
#pragma unroll 4
        for (int r = 0; r < 32; r++) {
            size_t wb = (size_t)(hc * 32 + r) * (NB * ND) + t * 8;
            float wv[8];
            if (BF) {
                uint4 u = *(const uint4*)((const __hip_bfloat16*)W1 + wb);
                wv[0] = __uint_as_float(u.x << 16); wv[1] = __uint_as_float(u.x & 0xffff0000u);
                wv[2] = __uint_as_float(u.y << 16); wv[3] = __uint_as_float(u.y & 0xffff0000u);
                wv[4] = __uint_as_float(u.z << 16); wv[5] = __uint_as_float(u.z & 0xffff0000u);
                wv[6] = __uint_as_float(u.w << 16); wv[7] = __uint_as_float(u.w & 0xffff0000u);
            } else {
                float4 a = *(const float4*)((const float*)W1 + wb);
                float4 b2v = *(const float4*)((const float*)W1 + wb + 4);
                wv[0]=a.x; wv[1]=a.y; wv[2]=a.z; wv[3]=a.w;
                wv[4]=b2v.x; wv[5]=b2v.y; wv[6]=b2v.z; wv[7]=b2v.w;
            }
            float s = 0.0f;
#pragma unroll
            for (int j = 0; j < 8; j++) s = fmaf(wv[j], fl[j], s);
            acc[r] = s;
        }
#pragma unroll
        for (int r = 0; r < 32; r++) red[t * 33 + r] = acc[r];
        __syncthreads();
        {
            int r = t >> 3, s8 = t & 7;
            float sum = 0.0f;
#pragma unroll
            for (int i = 0; i < 32; i++) sum += red[(s8 * 32 + i) * 33 + r];
            pr[r * 8 + s8] = sum;
        }
        __syncthreads();
        if (t < 32) {
            float h = ldf<BF>(b1, hc * 32 + t);
#pragma unroll
            for (int s8 = 0; s8 < 8; s8++) h += pr[t * 8 + s8];
            hbuf[g * HIDN + hc * 32 + t] = fmaxf(h, 0.0f);
        }
    }
    grid.sync();

    // ---- P4: MLP layer 2 (blocks 0..31) ----
    if (b < NG) {
        float* hs = scr;
        hs[t] = hbuf[b * HIDN + t];
        __syncthreads();
        int w = t >> 6, lane = t & 63;
        for (int c = w; c < NCLS; c += 4) {
            float p = hs[lane]       * ldf<BF>(W2, c * HIDN + lane)
                    + hs[lane + 64]  * ldf<BF>(W2, c * HIDN + lane + 64)
                    + hs[lane + 128] * ldf<BF>(W2, c * HIDN + lane + 128)
                    + hs[lane + 192] * ldf<BF>(W2, c * HIDN + lane + 192);
#pragma unroll
            for (int off = 32; off >= 1; off >>= 1) p += __shfl_xor(p, off);
            if (lane == 0) {
                float r = p + ldf<BF>(b2, c);
                if (BF) ((__hip_bfloat16*)outv)[b * NCLS + c] = __float2bfloat16(r);
                else    ((float*)outv)[b * NCLS + c] = r;
            }
        }
    }
}

__global__ __launch_bounds__(256) void k_all(const int* ei, const int* fc,
                                             const int* batch,
                                             const void* x, const void* nw,
                                             const void* v, const void* ew,
                                             const void* fw, const void* W1,
                                             const void* b1, const void* W2,
                                             const void* b2, float* wsf,
                                             void* outv) {
    __shared__ float scr[4 * HBINS * 64];          // 35.8 KB union scratch
    __shared__ unsigned cnt[64], base[64];
    cg::grid_group grid = cg::this_grid();
    bool bf = detect_bf(x), i64 = detect_i64(ei);
    if (bf)  { if (i64) all_body<true,true >(ei,fc,batch,x,nw,v,ew,fw,W1,b1,W2,b2,wsf,outv,scr,cnt,base,grid);
               else     all_body<true,false>(ei,fc,batch,x,nw,v,ew,fw,W1,b1,W2,b2,wsf,outv,scr,cnt,base,grid); }
    else     { if (i64) all_body<false,true >(ei,fc,batch,x,nw,v,ew,fw,W1,b1,W2,b2,wsf,outv,scr,cnt,base,grid);
               else     all_body<false,false>(ei,fc,batch,x,nw,v,ew,fw,W1,b1,W2,b2,wsf,outv,scr,cnt,base,grid); }
}

extern "C" void kernel_launch(void* const* d_in, const int* in_sizes, int n_in,
                              void* d_out, int out_size, void* d_ws, size_t ws_size,
                              hipStream_t stream) {
    const void* x  = d_in[0];
    const void* nw = d_in[1];
    const void* ew = d_in[2];
    const void* fw = d_in[3];
    const void* v  = d_in[4];
    const void* W1 = d_in[5];
    const void* b1 = d_in[6];
    const void* W2 = d_in[7];
    const void* b2 = d_in[8];
    const int* ei    = (const int*)d_in[9];
    const int* fc    = (const int*)d_in[10];
    const int* batch = (const int*)d_in[11];
    float* wsf = (float*)d_ws;
    void* outv = d_out;

    void* args[] = {(void*)&ei, (void*)&fc, (void*)&batch, (void*)&x, (void*)&nw,
                    (void*)&v, (void*)&ew, (void*)&fw, (void*)&W1, (void*)&b1,
                    (void*)&W2, (void*)&b2, (void*)&wsf, (void*)&outv};
    hipLaunchCooperativeKernel((const void*)k_all, dim3(GRID), dim3(BLK),
                               args, 0, stream);
}

// Round 13
// 140.473 us; speedup vs baseline: 3.5069x; 3.5069x over previous
//
#include <hip/hip_runtime.h>
#include <hip/hip_bf16.h>

// ---- problem constants ----
constexpr int NN = 16000, NE = 48000, NF = 32000;
constexpr int ND = 64, NB = 32, NG = 32;
constexpr int HIDN = 256, NCLS = 10;
constexpr int CHB = 32;                       // chunk-blocks per graph in k_ecc
constexpr int EFB = (NE + NF + 255) / 256;    // 313 hist/scatter blocks
constexpr int PREB = (NN * ND) / 256;         // 4000 blocks in k_pre
constexpr float KLOG = 144.26950408889634f;   // 100 * log2(e)
constexpr float DLT  = 9.307710457348151f;    // (2/31) * KLOG
constexpr float INV_DLT = 0.10743849569269015f; // 1/DLT
constexpr int HBINS = 35;                     // 32 real + 3 pad (max write jlo+3 <= 34)

// ---- ws word layout (ws_size = 268 MB measured; we use ~4.6 MB) ----
constexpr int NH_OFF   = 0;                   // [NN*ND] f32 node heights (4 MB)
constexpr int ECCF_OFF = NH_OFF + NN * ND;    // [NG*NB*ND]=65536 f32 ecc
constexpr int C32_OFF  = ECCF_OFF + NG*NB*ND; // [64] u32 hist (e:0..31, f:32..63)
constexpr int CUR_OFF  = C32_OFF + 64;        // [64] u32 scatter cursors
constexpr int NOFS_OFF = CUR_OFF + 64;        // [33] i32 node boundaries
constexpr int PE_OFF   = NOFS_OFF + 34;       // u16[NE] perm (24000 words)
constexpr int PF_OFF   = PE_OFF + NE / 2;     // u16[NF] perm (16000 words)
constexpr int HB_OFF   = PF_OFF + NF / 2;     // [NG*HIDN] f32 hidden acts
constexpr int ZERO_CNT = NG * NB * ND;        // eccf zeroed in k_pre

__device__ __forceinline__ int clamp_node(int n) {
    return ((unsigned)n < (unsigned)NN) ? n : 0;
}
template<bool BF> __device__ __forceinline__ float ldf(const void* p, int i) {
    return BF ? __bfloat162float(((const __hip_bfloat16*)p)[i]) : ((const float*)p)[i];
}
template<bool I64> __device__ __forceinline__ int ldi(const int* p, int i) {
    return I64 ? p[2 * i] : p[i];
}

// per-block dtype self-detection (wave-uniform via ballot)
__device__ __forceinline__ bool detect_bf(const void* xp) {
    const unsigned* xw = (const unsigned*)xp;
    unsigned w = xw[threadIdx.x & 63];
    return __ballot(((w >> 23) & 0xFFu) >= 200u) != 0ull;
}
__device__ __forceinline__ bool detect_i64(const int* eip) {
    const unsigned* eiw = (const unsigned*)eip;
    unsigned o = eiw[2 * (threadIdx.x & 63) + 1];
    return __ballot(o != 0u) == 0ull;
}

// 4-tap delta-histogram sigmoid (validated R12, absmax 1.0): 3 exact rcp taps +
// saturation step at T=14 (err <= 6.5e-5/element). Lane d owns column d of its
// wave's private copy: plain LDS RMW, no atomics.
__device__ __forceinline__ void accum_hist(float h, float s, float* hb) {
    const float KDEC = __builtin_amdgcn_exp2f(-DLT);
    float hkL = fmaf(h, KLOG, KLOG);              // t_j = hkL - j*DLT
    float fl = floorf((hkL - 14.0f) * INV_DLT);
    int jlo = (int)fl + 1;                        // first j with t_j < 14
    if (jlo >= 32) return;                        // everything ~0
    float t0 = fmaf(-(fl + 1.0f), DLT, hkL);      // t at jlo, in [4.69, 14)
    float e = __builtin_amdgcn_exp2f(t0);
    float prev = 0.0f;
#pragma unroll
    for (int m = 0; m < 3; m++) {
        float sig = __builtin_amdgcn_rcpf(1.0f + e);
        int idx = max(jlo + m, 0);
        hb[idx * 64] += s * (sig - prev);
        prev = sig; e *= KDEC;
    }
    int idx3 = max(jlo + 3, 0);
    hb[idx3 * 64] += s * (1.0f - prev);
}

// K0: fused prelude — node heights nh, zero eccf, node boundaries, e/f histogram.
template<bool BF, bool I64>
__device__ __forceinline__ void pre_body(const void* x, const void* nw, const void* v,
                                         const int* ei, const int* fc, const int* batch,
                                         float* wsf, int* wsi, unsigned* wsu,
                                         unsigned* hb) {
    int t = threadIdx.x;
    int gid = blockIdx.x * 256 + t;

    if (gid < ZERO_CNT) wsf[ECCF_OFF + gid] = 0.0f;

    if (gid < NN) {                                // node range boundaries
        int gn = ldi<I64>(batch, gid) & (NG - 1);
        int gp = (gid > 0) ? (ldi<I64>(batch, gid - 1) & (NG - 1)) : -1;
        for (int gg = gp + 1; gg <= gn; gg++) wsi[NOFS_OFF + gg] = gid;
        if (gid == NN - 1)
            for (int gg = gn + 1; gg <= NG; gg++) wsi[NOFS_OFF + gg] = NN;
    }

    {                                              // heights: gid in [0, NN*ND)
        int n = gid >> 6, d = gid & 63;
        float h = fmaf(ldf<BF>(x, n*3+2), ldf<BF>(v, 2*ND+d),
                  fmaf(ldf<BF>(x, n*3+1), ldf<BF>(v, ND+d),
                       ldf<BF>(x, n*3+0) * ldf<BF>(v, d))) * ldf<BF>(nw, n);
        wsf[NH_OFF + gid] = h;
    }

    if (blockIdx.x < EFB) {                        // histogram (block-uniform branch)
        if (t < 64) hb[t] = 0;
        __syncthreads();
        int id = blockIdx.x * 256 + t;
        if (id < NE + NF) {
            if (id < NE) atomicAdd(&hb[ldi<I64>(batch, clamp_node(ldi<I64>(ei, id))) & 31], 1u);
            else atomicAdd(&hb[32 + (ldi<I64>(batch, clamp_node(ldi<I64>(fc, id - NE))) & 31)], 1u);
        }
        __syncthreads();
        if (t < 64 && hb[t]) atomicAdd(&wsu[C32_OFF + t], hb[t]);
    }
}
__global__ __launch_bounds__(256) void k_pre(const void* __restrict__ x,
                                             const void* __restrict__ nw,
                                             const void* __restrict__ v,
                                             const int* __restrict__ ei,
                                             const int* __restrict__ fc,
                                             const int* __restrict__ batch,
                                             float* __restrict__ wsf,
                                             int* __restrict__ wsi,
                                             unsigned* __restrict__ wsu) {
    __shared__ unsigned hb[64];
    bool bf = detect_bf(x), i64 = detect_i64(ei);
    if (bf)  { if (i64) pre_body<true,true >(x,nw,v,ei,fc,batch,wsf,wsi,wsu,hb);
               else     pre_body<true,false>(x,nw,v,ei,fc,batch,wsf,wsi,wsu,hb); }
    else     { if (i64) pre_body<false,true >(x,nw,v,ei,fc,batch,wsf,wsi,wsu,hb);
               else     pre_body<false,false>(x,nw,v,ei,fc,batch,wsf,wsi,wsu,hb); }
}

// K1: single-pass scatter, all 32 graphs
template<bool I64>
__device__ __forceinline__ void scatter_body(const int* ei, const int* fc,
                                             const int* batch, unsigned* wsu,
                                             unsigned short* pe, unsigned short* pf,
                                             unsigned* cnt, unsigned* base, int* pstart) {
    int t = threadIdx.x;
    if (t < 64) cnt[t] = 0;
    __syncthreads();
    if (t == 0) {
        int acc = 0;
        for (int i = 0; i < 32; i++) { pstart[i] = acc; acc += (int)wsu[C32_OFF + i]; }
        acc = 0;
        for (int i = 0; i < 32; i++) { pstart[32+i] = acc; acc += (int)wsu[C32_OFF + 32 + i]; }
    }
    int id = blockIdx.x * 256 + t;
    int bin = 0; unsigned rank = 0; bool act = false;
    if (id < NE + NF) {
        if (id < NE) bin = ldi<I64>(batch, clamp_node(ldi<I64>(ei, id))) & 31;
        else         bin = 32 + (ldi<I64>(batch, clamp_node(ldi<I64>(fc, id - NE))) & 31);
        act = true;
        rank = atomicAdd(&cnt[bin], 1u);
    }
    __syncthreads();
    if (t < 64) base[t] = cnt[t] ? atomicAdd(&wsu[CUR_OFF + t], cnt[t]) : 0u;
    __syncthreads();
    if (act) {
        int pos = pstart[bin] + (int)(base[bin] + rank);
        if (bin < 32) { if (pos >= 0 && pos < NE) pe[pos] = (unsigned short)id; }
        else          { if (pos >= 0 && pos < NF) pf[pos] = (unsigned short)(id - NE); }
    }
}
__global__ __launch_bounds__(256) void k_scatter(const int* __restrict__ ei,
                                                 const int* __restrict__ fc,
                                                 const int* __restrict__ batch,
                                                 unsigned* __restrict__ wsu,
                                                 unsigned short* __restrict__ pe,
                                                 unsigned short* __restrict__ pf) {
    __shared__ unsigned cnt[64], base[64];
    __shared__ int pstart[64];
    if (detect_i64(ei)) scatter_body<true>(ei, fc, batch, wsu, pe, pf, cnt, base, pstart);
    else                scatter_body<false>(ei, fc, batch, wsu, pe, pf, cnt, base, pstart);
}

// K2: ecc via wave-private LDS delta-histograms (no atomics in the hot loop).
// grid = NG*CHB = 1024 blocks = 4/CU; wave-stream per element, lane = dir.
template<bool BF, bool I64>
__device__ __forceinline__ void ecc_body(const int* ei, const int* fc,
                                         const void* ew, const void* fw,
                                         const float* nh, const int* wsi,
                                         const unsigned* wsu, float* eccf,
                                         const unsigned short* pe,
                                         const unsigned short* pf,
                                         float* hist, int* sofs) {
    int t = threadIdx.x;
    int d = t & 63;
    int w = __builtin_amdgcn_readfirstlane(t) >> 6;
    int g  = blockIdx.x >> 5;                 // / CHB
    int cb = blockIdx.x & (CHB - 1);
    int sid = cb * 4 + w;
    const int S = CHB * 4;                    // 128 streams per graph

    for (int j = t; j < 4 * HBINS * 64; j += 256) hist[j] = 0.0f;
    if (t == 0) {
        int ea = 0, fa = 0;
        for (int i = 0; i < 32; i++) {
            if (i < g) { ea += (int)wsu[C32_OFF + i]; fa += (int)wsu[C32_OFF + 32 + i]; }
        }
        sofs[0] = ea; sofs[1] = (int)wsu[C32_OFF + g];
        sofs[2] = fa; sofs[3] = (int)wsu[C32_OFF + 32 + g];
    }
    __syncthreads();

    float* hb = hist + w * (HBINS * 64) + d;  // wave-private copy, lane-owned column

    // nodes (+1)
    int ns = wsi[NOFS_OFF + g], nend = wsi[NOFS_OFF + g + 1];
    for (int i = ns + sid; i < nend; i += S)
        accum_hist(nh[i * ND + d], 1.0f, hb);

    // edges (-1)
    int es = sofs[0], ee = min(sofs[0] + sofs[1], NE);
    for (int i = es + sid; i < ee; i += S) {
        int e = pe[i];
        int a = clamp_node(ldi<I64>(ei, e)), b = clamp_node(ldi<I64>(ei, NE + e));
        float h = fmaxf(nh[a * ND + d], nh[b * ND + d]) * ldf<BF>(ew, e);
        accum_hist(h, -1.0f, hb);
    }

    // faces (+1)
    int fs0 = sofs[2], fe = min(sofs[2] + sofs[3], NF);
    for (int i = fs0 + sid; i < fe; i += S) {
        int f = pf[i];
        int a = clamp_node(ldi<I64>(fc, f)), b = clamp_node(ldi<I64>(fc, NF + f));
        int c = clamp_node(ldi<I64>(fc, 2*NF + f));
        float h = fmaxf(fmaxf(nh[a*ND+d], nh[b*ND+d]), nh[c*ND+d]) * ldf<BF>(fw, f);
        accum_hist(h, 1.0f, hb);
    }

    __syncthreads();
    // collapse 4 wave copies with full block, then prefix over j; one atomic/(j,d)
    for (int o = t; o < HBINS * 64; o += 256)
        hist[o] += hist[HBINS*64 + o] + hist[2*HBINS*64 + o] + hist[3*HBINS*64 + o];
    __syncthreads();
    if (t < 64) {
        float run = 0.0f;
        float* eb = eccf + g * (NB * ND) + t;
        for (int j = 0; j < 32; j++) {
            run += hist[j * 64 + t];
            atomicAdd(eb + j * 64, run);
        }
    }
}
__global__ __launch_bounds__(256, 4) void k_ecc(const int* __restrict__ ei,
                                                const int* __restrict__ fc,
                                                const void* __restrict__ ew,
                                                const void* __restrict__ fw,
                                                const float* __restrict__ nh,
                                                const int* __restrict__ wsi,
                                                const unsigned* __restrict__ wsu,
                                                float* __restrict__ eccf,
                                                const unsigned short* __restrict__ pe,
                                                const unsigned short* __restrict__ pf,
                                                const void* __restrict__ x) {
    __shared__ float hist[4 * HBINS * 64];         // 35.8 KB, wave-private copies
    __shared__ int sofs[4];
    bool bf = detect_bf(x), i64 = detect_i64(ei);
    if (bf)  { if (i64) ecc_body<true,true >(ei,fc,ew,fw,nh,wsi,wsu,eccf,pe,pf,hist,sofs);
               else     ecc_body<true,false>(ei,fc,ew,fw,nh,wsi,wsu,eccf,pe,pf,hist,sofs); }
    else     { if (i64) ecc_body<false,true >(ei,fc,ew,fw,nh,wsi,wsu,eccf,pe,pf,hist,sofs);
               else     ecc_body<false,false>(ei,fc,ew,fw,nh,wsi,wsu,eccf,pe,pf,hist,sofs); }
}

// K3: MLP layer 1 + fused flat-output flush. grid = 32 graphs x 8 hid-chunks.
template<bool BF>
__device__ __forceinline__ void mlp1_body(const void* W1, const void* b1,
                                          const float* eccf, float* hbuf,
                                          void* outv, float* red, float* pr) {
    int g = blockIdx.x >> 3, hc = blockIdx.x & 7;
    int t = threadIdx.x;

    const float4* fp = (const float4*)(eccf + g * (NB * ND) + t * 8);
    float4 fa = fp[0], fb = fp[1];
    float fl[8] = {fa.x, fa.y, fa.z, fa.w, fb.x, fb.y, fb.z, fb.w};

    if (hc == 0) {                              // flush flat output (once per graph)
        int ob = NG * NCLS + g * (NB * ND) + t * 8;
        if (BF) {
#pragma unroll
            for (int j = 0; j < 8; j++)
                ((__hip_bfloat16*)outv)[ob + j] = __float2bfloat16(fl[j]);
        } else {
            ((float4*)((float*)outv + ob))[0] = fa;
            ((float4*)((float*)outv + ob))[1] = fb;
        }
    }

    float acc[32];
#pragma unroll
    for (int r = 0; r < 32; r++) acc[r] = 0.0f;
#pragma unroll 4
    for (int r = 0; r < 32; r++) {
        size_t wb = (size_t)(hc * 32 + r) * (NB * ND) + t * 8;
        float wv[8];
        if (BF) {
            uint4 u = *(const uint4*)((const __hip_bfloat16*)W1 + wb);
            wv[0] = __uint_as_float(u.x << 16); wv[1] = __uint_as_float(u.x & 0xffff0000u);
            wv[2] = __uint_as_float(u.y << 16); wv[3] = __uint_as_float(u.y & 0xffff0000u);
            wv[4] = __uint_as_float(u.z << 16); wv[5] = __uint_as_float(u.z & 0xffff0000u);
            wv[6] = __uint_as_float(u.w << 16); wv[7] = __uint_as_float(u.w & 0xffff0000u);
        } else {
            float4 a = *(const float4*)((const float*)W1 + wb);
            float4 b = *(const float4*)((const float*)W1 + wb + 4);
            wv[0]=a.x; wv[1]=a.y; wv[2]=a.z; wv[3]=a.w;
            wv[4]=b.x; wv[5]=b.y; wv[6]=b.z; wv[7]=b.w;
        }
        float s = 0.0f;
#pragma unroll
        for (int j = 0; j < 8; j++) s = fmaf(wv[j], fl[j], s);
        acc[r] = s;
    }

#pragma unroll
    for (int r = 0; r < 32; r++) red[t * 33 + r] = acc[r];
    __syncthreads();
    {
        int r = t >> 3, s8 = t & 7;
        float sum = 0.0f;
#pragma unroll
        for (int i = 0; i < 32; i++) sum += red[(s8 * 32 + i) * 33 + r];
        pr[r * 8 + s8] = sum;
    }
    __syncthreads();
    if (t < 32) {
        float h = ldf<BF>(b1, hc * 32 + t);
#pragma unroll
        for (int s8 = 0; s8 < 8; s8++) h += pr[t * 8 + s8];
        hbuf[g * HIDN + hc * 32 + t] = fmaxf(h, 0.0f);
    }
}
__global__ __launch_bounds__(256) void k_mlp1(const void* __restrict__ W1,
                                              const void* __restrict__ b1,
                                              const float* __restrict__ eccf,
                                              float* __restrict__ hbuf,
                                              void* __restrict__ outv,
                                              const void* __restrict__ x) {
    __shared__ float red[256 * 33];
    __shared__ float pr[256];
    if (detect_bf(x)) mlp1_body<true>(W1, b1, eccf, hbuf, outv, red, pr);
    else              mlp1_body<false>(W1, b1, eccf, hbuf, outv, red, pr);
}

// K4: MLP layer 2. one block per graph; wave per class, shuffle reduce.
template<bool BF>
__device__ __forceinline__ void mlp2_body(const void* W2, const void* b2,
                                          const float* hbuf, void* outv, float* hs) {
    int g = blockIdx.x, t = threadIdx.x;
    hs[t] = hbuf[g * HIDN + t];
    __syncthreads();
    int w = t >> 6, lane = t & 63;
    for (int c = w; c < NCLS; c += 4) {
        float p = hs[lane]        * ldf<BF>(W2, c * HIDN + lane)
                + hs[lane + 64]   * ldf<BF>(W2, c * HIDN + lane + 64)
                + hs[lane + 128]  * ldf<BF>(W2, c * HIDN + lane + 128)
                + hs[lane + 192]  * ldf<BF>(W2, c * HIDN + lane + 192);
#pragma unroll
        for (int off = 32; off >= 1; off >>= 1) p += __shfl_xor(p, off);
        if (lane == 0) {
            float r = p + ldf<BF>(b2, c);
            if (BF) ((__hip_bfloat16*)outv)[g * NCLS + c] = __float2bfloat16(r);
            else    ((float*)outv)[g * NCLS + c] = r;
        }
    }
}
__global__ __launch_bounds__(256) void k_mlp2(const void* __restrict__ W2,
                                              const void* __restrict__ b2,
                                              const float* __restrict__ hbuf,
                                              void* __restrict__ outv,
                                              const void* __restrict__ x) {
    __shared__ float hs[HIDN];
    if (detect_bf(x)) mlp2_body<true>(W2, b2, hbuf, outv, hs);
    else              mlp2_body<false>(W2, b2, hbuf, outv, hs);
}

extern "C" void kernel_launch(void* const* d_in, const int* in_sizes, int n_in,
                              void* d_out, int out_size, void* d_ws, size_t ws_size,
                              hipStream_t stream) {
    const void* x  = d_in[0];
    const void* nw = d_in[1];
    const void* ew = d_in[2];
    const void* fw = d_in[3];
    const void* v  = d_in[4];
    const void* W1 = d_in[5];
    const void* b1 = d_in[6];
    const void* W2 = d_in[7];
    const void* b2 = d_in[8];
    const int* ei    = (const int*)d_in[9];
    const int* fc    = (const int*)d_in[10];
    const int* batch = (const int*)d_in[11];

    float*    wsf = (float*)d_ws;
    unsigned* wsu = (unsigned*)d_ws;
    int*      wsi = (int*)d_ws;
    float*    nh   = wsf + NH_OFF;
    float*    eccf = wsf + ECCF_OFF;
    float*    hbuf = wsf + HB_OFF;
    unsigned short* pe = (unsigned short*)(wsi + PE_OFF);
    unsigned short* pf = (unsigned short*)(wsi + PF_OFF);

    hipMemsetAsync((char*)d_ws + (size_t)C32_OFF * 4, 0, 128 * 4, stream);

    k_pre<<<PREB, 256, 0, stream>>>(x, nw, v, ei, fc, batch, wsf, wsi, wsu);
    k_scatter<<<EFB, 256, 0, stream>>>(ei, fc, batch, wsu, pe, pf);
    k_ecc<<<NG * CHB, 256, 0, stream>>>(ei, fc, ew, fw, nh, wsi, wsu, eccf, pe, pf, x);
    k_mlp1<<<NG * 8, 256, 0, stream>>>(W1, b1, eccf, hbuf, d_out, x);
    k_mlp2<<<NG, 256, 0, stream>>>(W2, b2, hbuf, d_out, x);
}